// Round 14
// baseline (36.740 us; speedup 1.0000x reference)
//
#include <hip/hip_runtime.h>

#define N_Q   50000
#define N_S   50000
#define M_NB  32
#define K_PTS 15
#define CIN   64
#define COUT  64
#define THRSQ 0.0101f              // ||nb||^2 bound for any w>0 (exact: 0.009901)
#define NWG   784                  // phase-1 waves: 196 blocks x 256 thr / 64

// ws: [0, 4096) int counts[NWG]; [4096, 4096 + NWG*64*4) int worklist[NWG][64]
#define WL_OFF 4096

// ---------------- phase 1: scan (1 thread per query point) + zero out --------
// Thread t: 8 int4 neighbor loads (coalesced), 32 independent gathers (MLP=32),
// close = any(||nb||^2 < THRSQ). Wave-cooperative compaction into the wave's
// PRIVATE worklist segment via ballot + prefix popcount — no atomics anywhere.
__global__ __launch_bounds__(256) void scan_kernel(
    const float* __restrict__ query,     // [N,3]
    const float* __restrict__ support,   // [N0,3]
    const int*   __restrict__ neighbors, // [N,M]
    int*         __restrict__ counts,    // [NWG]
    int*         __restrict__ worklist,  // [NWG][64]
    float4*      __restrict__ out4)      // N_Q*COUT/4
{
    const int t  = blockIdx.x * 256 + threadIdx.x;  // query point id
    const int nt = gridDim.x * 256;

    // zero the output (independent; overlaps gather latency)
    const float4 z = make_float4(0.f, 0.f, 0.f, 0.f);
    for (int i = t; i < N_Q * COUT / 4; i += nt)
        out4[i] = z;

    bool close = false;
    if (t < N_Q) {
        const float qx = query[t * 3 + 0];
        const float qy = query[t * 3 + 1];
        const float qz = query[t * 3 + 2];
        const int4* nb4 = (const int4*)(neighbors + (size_t)t * M_NB);
        #pragma unroll
        for (int q8 = 0; q8 < 8; ++q8) {
            const int4 v = nb4[q8];                  // coalesced 128B/thread
            const int id[4] = { v.x, v.y, v.z, v.w };
            #pragma unroll
            for (int j = 0; j < 4; ++j) {
                const int  idx   = id[j];
                const bool valid = idx < N_S;        // idx==N_S: shadow, w==0
                const int  ic    = valid ? idx : 0;  // branchless clamped gather
                const float dx = support[ic * 3 + 0] - qx;
                const float dy = support[ic * 3 + 1] - qy;
                const float dz = support[ic * 3 + 2] - qz;
                const float d2 = dx * dx + dy * dy + dz * dz;
                close |= valid && (d2 < THRSQ);
            }
        }
    }

    const int lane = threadIdx.x & 63;
    const int wgid = t >> 6;                         // global wave id
    const unsigned long long mask = __ballot(close);
    if (close) {
        const int slot = (int)__popcll(mask & ((1ull << lane) - 1ull));
        worklist[wgid * 64 + slot] = t;
    }
    if (lane == 0) counts[wgid] = (int)__popcll(mask);  // written every call
}

// ---------------- phase 2: close points only (1 wave per point) --------------
// Block b owns segment b (~8 points, Poisson-balanced); 8 waves stride it.
// Per point: lanes 0-31 gather + distance; per active k: racc (c=lane) then
// wide GEMV — lane owns quad og=(lane&15)*4, c-subset cg=lane>>4, 16 dwordx4
// loads, 2 FMA chains, shfl_xor(16,32) reduce; lanes 0-15 store float4 row.
__global__ __launch_bounds__(512) void close_kernel(
    const float* __restrict__ query,
    const float* __restrict__ support,
    const int*   __restrict__ neighbors,
    const float* __restrict__ x,         // [N0,CIN]
    const float* __restrict__ kpts,      // [K,3]
    const float* __restrict__ weight,    // [K,CIN,COUT]
    const int*   __restrict__ counts,
    const int*   __restrict__ worklist,
    float*       __restrict__ out)       // [N,COUT]
{
    __shared__ float s_kx[K_PTS], s_ky[K_PTS], s_kz[K_PTS], s_kk[K_PTS];
    __shared__ float s_bc[8][CIN];

    const int tid = threadIdx.x;
    if (tid < K_PTS) {
        float kx = kpts[tid * 3 + 0];
        float ky = kpts[tid * 3 + 1];
        float kz = kpts[tid * 3 + 2];
        s_kx[tid] = kx; s_ky[tid] = ky; s_kz[tid] = kz;
        s_kk[tid] = kx * kx + ky * ky + kz * kz;   // same 3-term fp32 sum as ref
    }
    __syncthreads();

    const int wv   = tid >> 6;                    // 0..7
    const int lane = tid & 63;
    const int seg  = blockIdx.x;
    const int cnt  = counts[seg];
    const int og   = (lane & 15) * 4;
    const int cg   = lane >> 4;

    for (int i = wv; i < cnt; i += 8) {
        const int n = worklist[seg * 64 + i];

        int idx = N_S;
        float dx = 0.f, dy = 0.f, dz = 0.f, nn = 1e30f;
        if (lane < 32) {
            idx = neighbors[n * M_NB + lane];
            if (idx < N_S) {
                dx = support[idx * 3 + 0] - query[n * 3 + 0];
                dy = support[idx * 3 + 1] - query[n * 3 + 1];
                dz = support[idx * 3 + 2] - query[n * 3 + 2];
                nn = dx * dx + dy * dy + dz * dz;
            }
        }

        float4 tq = make_float4(0.f, 0.f, 0.f, 0.f);

        for (int k = 0; k < K_PTS; ++k) {
            float w = 0.f;
            if (nn < THRSQ) {
                float dot = dx * s_kx[k] + dy * s_ky[k] + dz * s_kz[k];
                float sq  = fmaxf(nn - 2.f * dot + s_kk[k], 0.f);  // ref expansion
                if (sq < 0.0025f)                   // sqrt(sq) < 0.05 => w > 0
                    w = 1.f - sqrtf(sq) * 20.f;     // 1/0.05 == 20 exactly
            }
            unsigned em = (unsigned)__ballot(w > 0.f);   // only lanes 0-31 set
            if (!em) continue;

            float racc = 0.f;
            do {
                const int src = __builtin_ctz(em); em &= em - 1;
                const float wsrc = __shfl(w,   src);
                const int   isrc = __shfl(idx, src);
                racc = fmaf(wsrc, x[(size_t)isrc * CIN + lane], racc);
            } while (em);

            s_bc[wv][lane] = racc;
            asm volatile("" ::: "memory");
            const float* wq = weight + (size_t)k * CIN * COUT + cg * COUT + og;
            float4 a0 = make_float4(0.f,0.f,0.f,0.f);
            float4 a1 = make_float4(0.f,0.f,0.f,0.f);
            #pragma unroll
            for (int q = 0; q < 16; q += 2) {
                const float4 v0 = *(const float4*)(wq + (q + 0) * 4 * COUT);
                const float4 v1 = *(const float4*)(wq + (q + 1) * 4 * COUT);
                const float xc0 = s_bc[wv][cg + 4 * q];
                const float xc1 = s_bc[wv][cg + 4 * q + 4];
                a0.x = fmaf(xc0, v0.x, a0.x); a0.y = fmaf(xc0, v0.y, a0.y);
                a0.z = fmaf(xc0, v0.z, a0.z); a0.w = fmaf(xc0, v0.w, a0.w);
                a1.x = fmaf(xc1, v1.x, a1.x); a1.y = fmaf(xc1, v1.y, a1.y);
                a1.z = fmaf(xc1, v1.z, a1.z); a1.w = fmaf(xc1, v1.w, a1.w);
            }
            a0.x += a1.x; a0.y += a1.y; a0.z += a1.z; a0.w += a1.w;
            a0.x += __shfl_xor(a0.x, 16); a0.y += __shfl_xor(a0.y, 16);
            a0.z += __shfl_xor(a0.z, 16); a0.w += __shfl_xor(a0.w, 16);
            a0.x += __shfl_xor(a0.x, 32); a0.y += __shfl_xor(a0.y, 32);
            a0.z += __shfl_xor(a0.z, 32); a0.w += __shfl_xor(a0.w, 32);
            tq.x += a0.x; tq.y += a0.y; tq.z += a0.z; tq.w += a0.w;
            asm volatile("" ::: "memory");
        }

        float4* row = (float4*)(out + (size_t)n * COUT);
        if (lane < 16) row[lane] = tq;              // overwrite pre-zeroed row
    }
}

extern "C" void kernel_launch(void* const* d_in, const int* in_sizes, int n_in,
                              void* d_out, int out_size, void* d_ws, size_t ws_size,
                              hipStream_t stream) {
    const float* query     = (const float*)d_in[0];
    const float* support   = (const float*)d_in[1];
    const int*   neighbors = (const int*)  d_in[2];
    const float* x         = (const float*)d_in[3];
    const float* kpts      = (const float*)d_in[4];
    const float* weight    = (const float*)d_in[5];
    float*       out       = (float*)d_out;

    int* counts   = (int*)d_ws;
    int* worklist = (int*)((char*)d_ws + WL_OFF);

    scan_kernel<<<196, 256, 0, stream>>>(
        query, support, neighbors, counts, worklist, (float4*)out);
    close_kernel<<<NWG, 512, 0, stream>>>(
        query, support, neighbors, x, kpts, weight, counts, worklist, out);
}

// Round 15
// 28.427 us; speedup vs baseline: 1.2924x; 1.2924x over previous
//
#include <hip/hip_runtime.h>

#define N_Q   50000
#define N_S   50000
#define M_NB  32
#define K_PTS 15
#define CIN   64
#define COUT  64
#define WPB   2                    // waves per block (128 threads, best: R9/R13)

// sc0 gather: read support row via L2 (bypass L1 miss path). Two loads
// (dwordx2 + dword) to stay in-bounds on the 12B row; early-clobber outputs
// so the address pair isn't overwritten between the two issues.
__device__ __forceinline__ void gather_support_sc0(
    const float* __restrict__ base, int idx, float& sx, float& sy, float& sz)
{
    const float* p = base + (size_t)idx * 3;
    float2 xy; float zz;
    asm volatile("global_load_dwordx2 %0, %2, off sc0\n\t"
                 "global_load_dword %1, %2, off offset:8 sc0\n\t"
                 "s_waitcnt vmcnt(0)"
                 : "=&v"(xy), "=&v"(zz)
                 : "v"(p)
                 : "memory");
    sx = xy.x; sy = xy.y; sz = zz;
}

// One wave per TWO query points: lanes 0-31 -> point A's 32 neighbors,
// lanes 32-63 -> point B's. Fully fused, single dispatch, no workspace.
//
// Sparsity (exact): w[k][m] = max(1 - d/0.05, 0), ||kp|| <= 0.0495, so w > 0
// requires ||nb||^2 < 0.009901 (0.0101 conservative). ~0.4% of pairs qualify.
//
// GEMV (per active (n,k)): lane L owns output quad og=(L&15)*4 and c-subset
// cg=L>>4: 16 dwordx4 weight loads (1KB/instr coalesced), 2 FMA chains,
// shfl_xor(16,32) reduce; lanes 0-15/16-31 store float4 rows.
__global__ __launch_bounds__(128) void kpconv_fused5(
    const float* __restrict__ query,     // [N,3]
    const float* __restrict__ support,   // [N0,3]
    const int*   __restrict__ neighbors, // [N,M]
    const float* __restrict__ x,         // [N0,CIN]
    const float* __restrict__ kpts,      // [K,3]
    const float* __restrict__ weight,    // [K,CIN,COUT]
    float*       __restrict__ out)       // [N,COUT]
{
    __shared__ float s_kx[K_PTS], s_ky[K_PTS], s_kz[K_PTS], s_kk[K_PTS];
    __shared__ float s_bc[WPB][CIN];     // per-wave broadcast buffer

    const int tid = threadIdx.x;
    if (tid < K_PTS) {
        float kx = kpts[tid * 3 + 0];
        float ky = kpts[tid * 3 + 1];
        float kz = kpts[tid * 3 + 2];
        s_kx[tid] = kx; s_ky[tid] = ky; s_kz[tid] = kz;
        s_kk[tid] = kx * kx + ky * ky + kz * kz;   // same 3-term fp32 sum as ref
    }
    __syncthreads();

    const int wv   = tid >> 6;                    // 0..1
    const int lane = tid & 63;
    const int base = blockIdx.x * (WPB * 2) + wv * 2;  // grid = N_Q/4 exactly
    const int h    = lane >> 5;                   // half: 0 -> point A, 1 -> B
    const int n    = base + h;                    // this lane's query point
    const int m    = lane & 31;

    const int idx = neighbors[n * M_NB + m];      // coalesced (2 rows/wave)

    float dx = 0.f, dy = 0.f, dz = 0.f, nn = 1e30f;
    if (idx < N_S) {                              // idx==N_S: shadow, w==0
        float sx, sy, sz;
        gather_support_sc0(support, idx, sx, sy, sz);   // L2-path gather
        dx = sx - query[n * 3 + 0];
        dy = sy - query[n * 3 + 1];
        dz = sz - query[n * 3 + 2];
        nn = dx * dx + dy * dy + dz * dz;
    }

    const int og = (lane & 15) * 4;               // output quad base
    const int cg = lane >> 4;                     // c-subset 0..3

    float4 toutA = make_float4(0.f, 0.f, 0.f, 0.f);
    float4 toutB = make_float4(0.f, 0.f, 0.f, 0.f);

    if (__ballot(nn < 0.0101f)) {                 // ~23% of waves
        for (int k = 0; k < K_PTS; ++k) {
            float w = 0.f;
            if (nn < 0.0101f) {
                float dot = dx * s_kx[k] + dy * s_ky[k] + dz * s_kz[k];
                float sq  = fmaxf(nn - 2.f * dot + s_kk[k], 0.f);  // ref expansion
                if (sq < 0.0025f)                  // sqrt(sq) < 0.05 => w > 0
                    w = 1.f - sqrtf(sq) * 20.f;    // 1/0.05 == 20 exactly
            }
            const unsigned long long em = __ballot(w > 0.f);
            if (!em) continue;                     // common: k has no hits

            const float* wk = weight + (size_t)k * CIN * COUT;
            const float* wq = wk + cg * COUT + og; // lane's first quad

            unsigned emA = (unsigned)(em & 0xffffffffull);   // point A events
            if (emA) {
                float racc = 0.f;
                do {
                    const int src = __builtin_ctz(emA); emA &= emA - 1;
                    const float wsrc = __shfl(w,   src);
                    const int   isrc = __shfl(idx, src);
                    racc = fmaf(wsrc, x[(size_t)isrc * CIN + lane], racc);
                } while (emA);
                s_bc[wv][lane] = racc;
                asm volatile("" ::: "memory");
                float4 a0 = make_float4(0.f,0.f,0.f,0.f);
                float4 a1 = make_float4(0.f,0.f,0.f,0.f);
                #pragma unroll
                for (int i = 0; i < 16; i += 2) {
                    const float4 v0 = *(const float4*)(wq + (i + 0) * 4 * COUT);
                    const float4 v1 = *(const float4*)(wq + (i + 1) * 4 * COUT);
                    const float xc0 = s_bc[wv][cg + 4 * i];
                    const float xc1 = s_bc[wv][cg + 4 * i + 4];
                    a0.x = fmaf(xc0, v0.x, a0.x); a0.y = fmaf(xc0, v0.y, a0.y);
                    a0.z = fmaf(xc0, v0.z, a0.z); a0.w = fmaf(xc0, v0.w, a0.w);
                    a1.x = fmaf(xc1, v1.x, a1.x); a1.y = fmaf(xc1, v1.y, a1.y);
                    a1.z = fmaf(xc1, v1.z, a1.z); a1.w = fmaf(xc1, v1.w, a1.w);
                }
                a0.x += a1.x; a0.y += a1.y; a0.z += a1.z; a0.w += a1.w;
                a0.x += __shfl_xor(a0.x, 16); a0.y += __shfl_xor(a0.y, 16);
                a0.z += __shfl_xor(a0.z, 16); a0.w += __shfl_xor(a0.w, 16);
                a0.x += __shfl_xor(a0.x, 32); a0.y += __shfl_xor(a0.y, 32);
                a0.z += __shfl_xor(a0.z, 32); a0.w += __shfl_xor(a0.w, 32);
                toutA.x += a0.x; toutA.y += a0.y;
                toutA.z += a0.z; toutA.w += a0.w;
                asm volatile("" ::: "memory");
            }

            unsigned emB = (unsigned)(em >> 32);             // point B events
            if (emB) {
                float racc = 0.f;
                do {
                    const int src = 32 + __builtin_ctz(emB); emB &= emB - 1;
                    const float wsrc = __shfl(w,   src);
                    const int   isrc = __shfl(idx, src);
                    racc = fmaf(wsrc, x[(size_t)isrc * CIN + lane], racc);
                } while (emB);
                s_bc[wv][lane] = racc;
                asm volatile("" ::: "memory");
                float4 a0 = make_float4(0.f,0.f,0.f,0.f);
                float4 a1 = make_float4(0.f,0.f,0.f,0.f);
                #pragma unroll
                for (int i = 0; i < 16; i += 2) {
                    const float4 v0 = *(const float4*)(wq + (i + 0) * 4 * COUT);
                    const float4 v1 = *(const float4*)(wq + (i + 1) * 4 * COUT);
                    const float xc0 = s_bc[wv][cg + 4 * i];
                    const float xc1 = s_bc[wv][cg + 4 * i + 4];
                    a0.x = fmaf(xc0, v0.x, a0.x); a0.y = fmaf(xc0, v0.y, a0.y);
                    a0.z = fmaf(xc0, v0.z, a0.z); a0.w = fmaf(xc0, v0.w, a0.w);
                    a1.x = fmaf(xc1, v1.x, a1.x); a1.y = fmaf(xc1, v1.y, a1.y);
                    a1.z = fmaf(xc1, v1.z, a1.z); a1.w = fmaf(xc1, v1.w, a1.w);
                }
                a0.x += a1.x; a0.y += a1.y; a0.z += a1.z; a0.w += a1.w;
                a0.x += __shfl_xor(a0.x, 16); a0.y += __shfl_xor(a0.y, 16);
                a0.z += __shfl_xor(a0.z, 16); a0.w += __shfl_xor(a0.w, 16);
                a0.x += __shfl_xor(a0.x, 32); a0.y += __shfl_xor(a0.y, 32);
                a0.z += __shfl_xor(a0.z, 32); a0.w += __shfl_xor(a0.w, 32);
                toutB.x += a0.x; toutB.y += a0.y;
                toutB.z += a0.z; toutB.w += a0.w;
                asm volatile("" ::: "memory");
            }
        }
    }

    // Lane L holds the output quad og=(L&15)*4 (replicated over cg groups).
    float4* rowA = (float4*)(out + (size_t)(base + 0) * COUT);
    float4* rowB = (float4*)(out + (size_t)(base + 1) * COUT);
    if (lane < 16)       rowA[lane]      = toutA;
    else if (lane < 32)  rowB[lane - 16] = toutB;
}

extern "C" void kernel_launch(void* const* d_in, const int* in_sizes, int n_in,
                              void* d_out, int out_size, void* d_ws, size_t ws_size,
                              hipStream_t stream) {
    const float* query     = (const float*)d_in[0];
    const float* support   = (const float*)d_in[1];
    const int*   neighbors = (const int*)  d_in[2];
    const float* x         = (const float*)d_in[3];
    const float* kpts      = (const float*)d_in[4];
    const float* weight    = (const float*)d_in[5];
    float*       out       = (float*)d_out;

    kpconv_fused5<<<N_Q / 4, 128, 0, stream>>>(    // 12500 blocks, 2 waves
        query, support, neighbors, x, kpts, weight, out);
}